// Round 18
// baseline (149.705 us; speedup 1.0000x reference)
//
#include <hip/hip_runtime.h>
#include <stdint.h>

typedef unsigned long long u64;
typedef unsigned int u32;
typedef unsigned short u16;
typedef float f32x4 __attribute__((ext_vector_type(4)));

#define NBINS 512
#define CAP 256          // per-head candidate cap; excluded alloc <= e^-1/257 ~ 1.4e-3
#define POOLCAP 1024     // = 4*CAP: provably holds all heads' candidates
#define LOG_CUT (-30.0f)
#define NT 1024          // 16 waves/block; 512 blocks -> 2 blocks/CU -> 32 waves/CU
#define MWW 256          // bitmap words for specialized M=16384 (TW*MWW == NT)

// Bucket = pure monotone function of sort-key bits (nn = 1-ue, f32 in [0,1]).
__device__ __forceinline__ int bucket_of(u32 nnbits) {
    u32 d = 0x3F800000u - nnbits;
    if (d == 0u) d = 1u;
    const int e = 31 - __builtin_clz(d);                    // 0..29
    const u32 sub = (e >= 4) ? ((d >> (e - 4)) & 15u) : ((d << (4 - e)) & 15u);
    int v = (e << 4) | (int)sub;
    if (v > NBINS - 1) v = NBINS - 1;
    return (NBINS - 1) - v;
}

__device__ __forceinline__ void nt_store4(float* p, float4 v) {
    f32x4 nv;
    nv.x = v.x; nv.y = v.y; nv.z = v.z; nv.w = v.w;
    __builtin_nontemporal_store(nv, (f32x4*)p);
}

// Single-wave (wave 0) suffix scan over hC with mass bound mB.
// lane l covers x in [NBINS-8(l+1), NBINS-8l). Writes xs (max x with sw<=LOG_CUT,
// gated x>=gate) and xc (min x with sc<=capv, gated x>=gate) to outXs/outXc.
__device__ __forceinline__ void wave0_scan(const u32* hC, const float* mB,
                                           int gate, u32 capv, bool wantXs,
                                           int* outXs, int* outXc, int lane) {
    const int x0 = NBINS - 8 * (lane + 1);
    // pass 1: chunk totals
    u32 csum = 0; float wsum = 0.f;
    #pragma unroll
    for (int j = 0; j < 8; ++j) {
        const u32 c = hC[x0 + j];
        csum += c; wsum += mB[x0 + j] * (float)c;
    }
    // inclusive lane scan (lane gets sum over lanes <= l, i.e. all higher-x chunks + own)
    u32 ics = csum; float iws = wsum;
    #pragma unroll
    for (int off = 1; off < 64; off <<= 1) {
        const u32 oc = __shfl_up(ics, off);
        const float ow = __shfl_up(iws, off);
        if (lane >= off) { ics += oc; iws += ow; }
    }
    u32 rc = ics - csum; float rw = iws - wsum;   // exclusive: higher chunks only
    // pass 2: running suffix, high x -> low x within chunk
    int myxs = -1, myxc = NBINS;
    #pragma unroll
    for (int j = 7; j >= 0; --j) {
        const int x = x0 + j;
        const u32 c = hC[x];
        rc += c; rw += mB[x] * (float)c;
        if (x >= gate) {
            if (wantXs && rw <= LOG_CUT && x > myxs) myxs = x;
            if (rc <= capv && x < myxc) myxc = x;
        }
    }
    // wave reduce
    #pragma unroll
    for (int off = 1; off < 64; off <<= 1) {
        const int oxs = __shfl_xor(myxs, off);
        const int oxc = __shfl_xor(myxc, off);
        if (oxs > myxs) myxs = oxs;
        if (oxc < myxc) myxc = oxc;
    }
    if (lane == 0) { *outXs = myxs; *outXc = myxc; }
}

// R17 structure (143.7us) + barrier diet: single-wave scans, sentinel rank
// (no K readback), idle-wave resets, deferred 4-head-parallel bitmap prefix.
template <int TW, int TR>
__global__ __launch_bounds__(NT, 8)
void fused_kernel(const float* __restrict__ ww,    // [B,W,M]
                  const float* __restrict__ fg,    // [B,R]
                  const float* __restrict__ rw,    // [B,R,M]
                  const float* __restrict__ prev,  // [B,M]
                  const float* __restrict__ wgt,   // [B,W]
                  float* __restrict__ out_usage,   // [B,M]
                  float* __restrict__ out_alloc,   // [B,W,M]
                  int B, int W, int R, int M)
{
    __shared__ u64   poolKey[POOLCAP];
    __shared__ float poolLg[POOLCAP];
    __shared__ u64   candKey[CAP];
    __shared__ float candLg[CAP];
    __shared__ u16   candPos[CAP];
    __shared__ float sPart[3][CAP];
    __shared__ u32   hC[NBINS];
    __shared__ float mB[NBINS];
    __shared__ u32   wvS[16];
    __shared__ int   misc[6];   // [0]=pool cnt,[1]=xs,[2]=xc,[3]=pc,[4]=cand cnt
    __shared__ u64   bmS[TW > 0 ? TW : 1][MWW];
    __shared__ u32   boS[TW > 0 ? TW : 1][MWW];
    __shared__ float valS[TW > 0 ? TW : 1][CAP];

    const int Wl = TW > 0 ? TW : W;
    const int Rl = TR > 0 ? TR : R;
    const int b = blockIdx.x;
    const int t = threadIdx.x;
    const int lane = t & 63;
    const int wid = t >> 6;

    const float C1 = (float)(1.0 - 1e-6);
    const float CE = 1e-6f;
    const size_t rowOff = (size_t)b * M;

    if (t < NBINS) {
        hC[t] = 0u;
        const int v = NBINS - 1 - t;
        const int e = v >> 4;
        const u32 sub = (u32)(v & 15);
        const int sh = e >= 4 ? e - 4 : 0;
        u64 dhi64 = ((u64)(17u + sub) << sh) + 1u;
        u32 dhi = dhi64 > 0x3F800000ull ? 0x3F800000u : (u32)dhi64;
        const float nnlo = __uint_as_float(0x3F800000u - dhi);
        float ueub = 1.0f - nnlo;
        ueub = ueub < 1e-38f ? 1e-38f : (ueub > 0.9999999f ? 0.9999999f : ueub);
        mB[t] = __log2f(ueub);
    }
    if (TW > 0 && t < TW * MWW) bmS[t >> 8][t & (MWW - 1)] = 0ull;
    if (t == 0) { misc[0] = 0; misc[3] = NBINS; misc[4] = 0; }
    __syncthreads();                                             // B0

    // ---------------- Phase S: streaming + usage store + inline hist ----------------
    {
        float frs[TR > 0 ? TR : 8];
        #pragma unroll
        for (int r = 0; r < Rl; ++r) frs[r] = fg[(size_t)b * Rl + r];

        for (int m = t * 4; m < M; m += NT * 4) {
            const float4 pv = *(const float4*)(prev + rowOff + m);
            float pr0 = 1.f, pr1 = 1.f, pr2 = 1.f, pr3 = 1.f;
            #pragma unroll
            for (int w = 0; w < Wl; ++w) {
                const float4 a = *(const float4*)(ww + ((size_t)b * Wl + w) * M + m);
                pr0 *= (1.0f - a.x); pr1 *= (1.0f - a.y);
                pr2 *= (1.0f - a.z); pr3 *= (1.0f - a.w);
            }
            float u0 = pv.x + (1.0f - pv.x) * (1.0f - pr0);
            float u1 = pv.y + (1.0f - pv.y) * (1.0f - pr1);
            float u2 = pv.z + (1.0f - pv.z) * (1.0f - pr2);
            float u3 = pv.w + (1.0f - pv.w) * (1.0f - pr3);
            float f0 = 1.f, f1 = 1.f, f2 = 1.f, f3 = 1.f;
            #pragma unroll
            for (int r = 0; r < Rl; ++r) {
                const float fr = frs[r];
                const float4 a = *(const float4*)(rw + ((size_t)b * Rl + r) * M + m);
                f0 *= (1.0f - fr * a.x); f1 *= (1.0f - fr * a.y);
                f2 *= (1.0f - fr * a.z); f3 *= (1.0f - fr * a.w);
            }
            float4 uo;
            uo.x = u0 * f0; uo.y = u1 * f1; uo.z = u2 * f2; uo.w = u3 * f3;
            *(float4*)(out_usage + rowOff + m) = uo;    // regular store: L2-hot
            if (TW == 0) {
                const float4 z = make_float4(0.f, 0.f, 0.f, 0.f);
                for (int w = 0; w < Wl; ++w)
                    nt_store4(out_alloc + ((size_t)b * Wl + w) * M + m, z);
            }
            const float ua[4] = {uo.x, uo.y, uo.z, uo.w};
            #pragma unroll
            for (int j = 0; j < 4; ++j) {
                const float nn = 1.0f - (CE + C1 * ua[j]);
                atomicAdd(&hC[bucket_of(__float_as_uint(nn))], 1u);
            }
        }
    }
    __syncthreads();                                             // B1

    // ---------------- Pool cut (single-wave) ----------------
    if (wid == 0) wave0_scan(hC, mB, 0, (u32)POOLCAP, false, &misc[1], &misc[3], lane);
    __syncthreads();                                             // B2
    const int pc = misc[3];

    // ---------------- Pool build: L2-hot usage re-read ----------------
    for (int m = t * 4; m < M; m += NT * 4) {
        const float4 uu = *(const float4*)(out_usage + rowOff + m);
        const float ua[4] = {uu.x, uu.y, uu.z, uu.w};
        #pragma unroll
        for (int j = 0; j < 4; ++j) {
            const float ue = CE + C1 * ua[j];
            const float nn = 1.0f - ue;
            const u32 nnbits = __float_as_uint(nn);
            const int bkt = bucket_of(nnbits);
            const bool pred = (bkt >= pc) && (pc < NBINS);
            const u64 mask = __ballot(pred);
            const int cnt = __popcll(mask);
            if (cnt) {
                int base = 0;
                if (lane == 0) base = atomicAdd(&misc[0], cnt);
                base = __shfl(base, 0);
                if (pred) {
                    const int pos = base + __popcll(mask & ((1ull << lane) - 1));
                    if (pos < POOLCAP) {
                        poolKey[pos] = (((u64)(~nnbits)) << 16) | (u64)(u32)(m + j);
                        poolLg[pos] = __log2f(ue);
                    }
                }
            }
        }
    }
    __syncthreads();                                             // B3
    int P = misc[0]; if (P > POOLCAP) P = POOLCAP;

    float myAl[TW > 0 ? TW : 1];
    int   myIdx[TW > 0 ? TW : 1];
    #pragma unroll
    for (int i = 0; i < (TW > 0 ? TW : 1); ++i) myIdx[i] = -1;

    // ---------------- Phase H: per write head ----------------
    #pragma unroll
    for (int i = 0; i < Wl; ++i) {
        const float wgi = wgt[(size_t)b * Wl + i];
        float* orow = out_alloc + ((size_t)b * Wl + i) * M;

        // scan region: wave0 scans; idle waves reset candKey sentinels + counter
        if (wid == 0) wave0_scan(hC, mB, pc, (u32)CAP, true, &misc[1], &misc[2], lane);
        if (t >= 256 && t < 256 + CAP) candKey[t - 256] = ~0ull;
        if (t == 576) misc[4] = 0;
        __syncthreads();                                         // Bh1
        const int xs = misc[1];
        const int xc = misc[2];
        const int cut = (xs > xc) ? xs : xc;

        // compact candidates from pool (1 iter: POOLCAP == NT)
        if (t < P) {
            const u64 key = poolKey[t];
            const u32 nnbits = ~((u32)(key >> 16));
            const int bkt = bucket_of(nnbits);
            const bool pred = (bkt >= cut) && (cut < NBINS);
            const u64 mask = __ballot(pred);
            const int cnt = __popcll(mask);
            if (cnt) {
                int base = 0;
                if (lane == 0) base = atomicAdd(&misc[4], cnt);
                base = __shfl(base, 0);
                if (pred) {
                    const int pos = base + __popcll(mask & ((1ull << lane) - 1));
                    if (pos < CAP) {
                        candKey[pos] = key;
                        candLg[pos] = poolLg[t];
                        candPos[pos] = (u16)t;
                    }
                }
            }
        }
        __syncthreads();                                         // Bh2

        // 4-way sentinel-safe rank: fixed 64-iter loops, no K needed
        const int c = t & (CAP - 1);
        const int g = t >> 8;
        const u64 mykey = candKey[c];
        float Sp = 0.0f;
        {
            const int k0 = g * (CAP / 4);
            #pragma unroll 4
            for (int k = k0; k < k0 + CAP / 4; ++k) {
                if (candKey[k] < mykey) Sp += candLg[k];
            }
        }
        if (g > 0) sPart[g - 1][c] = Sp;
        __syncthreads();                                         // Bh3

        if (t < CAP && mykey != ~0ull) {
            const float S = Sp + sPart[0][t] + sPart[1][t] + sPart[2][t];
            const u32 nnbits = ~((u32)(mykey >> 16));
            const float nn = __uint_as_float(nnbits);
            const int idx = (int)(mykey & 0xFFFFull);
            const float al = nn * __builtin_exp2f(S);
            if (al != 0.0f) {
                if (TW > 0) {
                    myAl[i] = al; myIdx[i] = idx;
                    atomicOr(&bmS[i][idx >> 6], 1ull << (idx & 63));
                } else {
                    orow[idx] = al;
                }
                if (i + 1 < Wl) {
                    const float ucur = (1.0f - nn - CE) / C1;
                    const float unew = ucur + ((1.0f - ucur) * wgi) * al;
                    const float nn2 = 1.0f - (CE + C1 * unew);
                    const u32 nn2bits = __float_as_uint(nn2);
                    const int p = (int)candPos[t];
                    poolKey[p] = (((u64)(~nn2bits)) << 16) | (u64)(u32)idx;
                    poolLg[p] = __log2f(1.0f - nn2);
                    const int bold = bucket_of(nnbits);
                    const int bnew = bucket_of(nn2bits);
                    if (bnew != bold) {
                        atomicSub(&hC[bold], 1u);
                        atomicAdd(&hC[bnew], 1u);
                    }
                }
            }
        }
        __syncthreads();                                         // Bh4
    }

    // ---------------- Deferred: 4-head-parallel bitmap prefix + deposit + sweep ----------------
    if (TW > 0) {
        // thread t: head h = t>>8, word w = t&255 (TW*MWW == NT)
        const int h = t >> 8;
        const int w = t & (MWW - 1);
        const u32 mycnt = (u32)__popcll(bmS[h][w]);
        u32 inc = mycnt;
        #pragma unroll
        for (int off = 1; off < 64; off <<= 1) {
            const u32 o = __shfl_up(inc, off);
            if (lane >= off) inc += o;
        }
        if (lane == 63) wvS[wid] = inc;
        __syncthreads();                                         // Be1
        {
            u32 add = 0;
            const int w0 = h * 4;          // first wave of this head
            for (int q = w0; q < wid; ++q) add += wvS[q];
            boS[h][w] = add + inc - mycnt;
        }
        __syncthreads();                                         // Be2
        #pragma unroll
        for (int i = 0; i < TW; ++i) {
            if (myIdx[i] >= 0) {
                const u64 wb = bmS[i][myIdx[i] >> 6];
                const int xr = (int)boS[i][myIdx[i] >> 6]
                             + (int)__popcll(wb & ((1ull << (myIdx[i] & 63)) - 1));
                valS[i][xr] = myAl[i];
            }
        }
        __syncthreads();                                         // Be3

        for (int m4 = t * 4; m4 < M; m4 += NT * 4) {
            const int word = m4 >> 6;
            const int bit0 = m4 & 63;
            #pragma unroll
            for (int w2 = 0; w2 < TW; ++w2) {
                const u64 wb = bmS[w2][word];
                float4 o = make_float4(0.f, 0.f, 0.f, 0.f);
                if ((wb >> bit0) & 15ull) {
                    int base = (int)boS[w2][word]
                             + (int)__popcll(wb & ((1ull << bit0) - 1));
                    float* op = &o.x;
                    #pragma unroll
                    for (int j = 0; j < 4; ++j) {
                        if ((wb >> (bit0 + j)) & 1ull) op[j] = valS[w2][base++];
                    }
                }
                nt_store4(out_alloc + ((size_t)b * TW + w2) * M + m4, o);
            }
        }
    }
}

extern "C" void kernel_launch(void* const* d_in, const int* in_sizes, int n_in,
                              void* d_out, int out_size, void* d_ws, size_t ws_size,
                              hipStream_t stream) {
    const float* ww   = (const float*)d_in[0];
    const float* fg   = (const float*)d_in[1];
    const float* rw   = (const float*)d_in[2];
    const float* prev = (const float*)d_in[3];
    const float* wgt  = (const float*)d_in[4];
    const int BWM = in_sizes[0];
    const int BR  = in_sizes[1];
    const int BM  = in_sizes[3];
    const int BW  = in_sizes[4];
    const int M = BWM / BW;
    const int B = BM / M;
    const int W = BW / B;
    const int R = BR / B;

    float* out_usage = (float*)d_out;
    float* out_alloc = out_usage + (size_t)BM;

    if (W == 4 && R == 8 && M == 16384) {
        hipLaunchKernelGGL((fused_kernel<4, 8>), dim3(B), dim3(NT), 0, stream,
                           ww, fg, rw, prev, wgt, out_usage, out_alloc, B, W, R, M);
    } else {
        hipLaunchKernelGGL((fused_kernel<0, 0>), dim3(B), dim3(NT), 0, stream,
                           ww, fg, rw, prev, wgt, out_usage, out_alloc, B, W, R, M);
    }
}

// Round 19
// 143.628 us; speedup vs baseline: 1.0423x; 1.0423x over previous
//
#include <hip/hip_runtime.h>
#include <stdint.h>

typedef unsigned long long u64;
typedef unsigned int u32;
typedef unsigned short u16;
typedef float f32x4 __attribute__((ext_vector_type(4)));

#define NBINS 512
#define CAP 256          // per-head candidate cap; excluded alloc <= e^-1/257 ~ 1.4e-3
#define POOLCAP 1024     // = CAP + 3*CAP: provably holds all heads' candidates
#define LOG_CUT (-30.0f)
#define NT 1024          // 16 waves/block; 512 blocks -> 2 blocks/CU -> 32 waves/CU
#define MWW 256          // bitmap words for specialized M=16384

// Bucket = pure monotone function of sort-key bits (nn = 1-ue, f32 in [0,1]).
// d = bits(1.0f)-bits(nn) grows as usage grows; 16 sub-bins/octave of d.
// HIGH bucket = small usage = candidate side. No transcendentals.
__device__ __forceinline__ int bucket_of(u32 nnbits) {
    u32 d = 0x3F800000u - nnbits;
    if (d == 0u) d = 1u;
    const int e = 31 - __builtin_clz(d);                    // 0..29
    const u32 sub = (e >= 4) ? ((d >> (e - 4)) & 15u) : ((d << (4 - e)) & 15u);
    int v = (e << 4) | (int)sub;
    if (v > NBINS - 1) v = NBINS - 1;
    return (NBINS - 1) - v;
}

__device__ __forceinline__ void nt_store4(float* p, float4 v) {
    f32x4 nv;
    nv.x = v.x; nv.y = v.y; nv.z = v.z; nv.w = v.w;
    __builtin_nontemporal_store(nv, (f32x4*)p);
}

// R16 structure (146us) + tail diet: POOLCAP 1024 (1-iter compact),
// 4-way-parallel rank (64 serial iters), LOG_CUT -30 (smaller K).
// [R19: verbatim revert to the measured-best R17 kernel, 143.7us]
template <int TW, int TR>
__global__ __launch_bounds__(NT, 8)
void fused_kernel(const float* __restrict__ ww,    // [B,W,M]
                  const float* __restrict__ fg,    // [B,R]
                  const float* __restrict__ rw,    // [B,R,M]
                  const float* __restrict__ prev,  // [B,M]
                  const float* __restrict__ wgt,   // [B,W]
                  float* __restrict__ out_usage,   // [B,M]
                  float* __restrict__ out_alloc,   // [B,W,M]
                  int B, int W, int R, int M)
{
    __shared__ u64   poolKey[POOLCAP];  // (~nnbits)<<16 | idx  (asc == nonusage desc)
    __shared__ float poolLg[POOLCAP];   // log2(ue_b) per pool element
    __shared__ u64   candKey[CAP];
    __shared__ float candLg[CAP];
    __shared__ u16   candPos[CAP];      // pool slot of candidate
    __shared__ float sPart[3][CAP];     // rank partial sums, groups 1..3
    __shared__ u32   hC[NBINS];         // persistent across heads (incremental)
    __shared__ float mB[NBINS];         // per-bucket upper bound of log2(ue)
    __shared__ u32   tc[16];
    __shared__ float twv[16];
    __shared__ int   misc[6];           // [0]=pool cnt,[1]=xs,[2]=xc,[3]=pc,[4]=cand cnt
    __shared__ u64   bmS[TW > 0 ? TW : 1][MWW];   // per-head candidate bitmap
    __shared__ u32   boS[TW > 0 ? TW : 1][MWW];   // per-word exclusive popcount prefix
    __shared__ float valS[TW > 0 ? TW : 1][CAP];  // values in row-rank order

    const int Wl = TW > 0 ? TW : W;
    const int Rl = TR > 0 ? TR : R;
    const int b = blockIdx.x;
    const int t = threadIdx.x;
    const int lane = t & 63;
    const int wid = t >> 6;

    const float C1 = (float)(1.0 - 1e-6);
    const float CE = 1e-6f;
    const size_t rowOff = (size_t)b * M;

    // init hist + mass-bound table + bitmaps (once)
    if (t < NBINS) {
        hC[t] = 0u;
        const int v = NBINS - 1 - t;          // (e<<4)|sub
        const int e = v >> 4;
        const u32 sub = (u32)(v & 15);
        const int sh = e >= 4 ? e - 4 : 0;
        u64 dhi64 = ((u64)(17u + sub) << sh) + 1u;   // safe upper bound of d in bucket
        u32 dhi = dhi64 > 0x3F800000ull ? 0x3F800000u : (u32)dhi64;
        const float nnlo = __uint_as_float(0x3F800000u - dhi);
        float ueub = 1.0f - nnlo;
        ueub = ueub < 1e-38f ? 1e-38f : (ueub > 0.9999999f ? 0.9999999f : ueub);
        mB[t] = __log2f(ueub);                // >= log2(ue) for bucket members
    }
    if (TW > 0 && t < TW * MWW) bmS[t >> 8][t & (MWW - 1)] = 0ull;
    if (t == 0) { misc[0] = 0; misc[3] = NBINS; }
    __syncthreads();

    // ---------------- Phase S: READ-ONLY streaming + usage store + hist ----------------
    // usage = (prev + (1-prev)*(1-prod_w(1-ww))) * prod_r(1-fg*rw), ref f32 op order
    {
        float frs[TR > 0 ? TR : 8];
        #pragma unroll
        for (int r = 0; r < Rl; ++r) frs[r] = fg[(size_t)b * Rl + r];

        for (int m = t * 4; m < M; m += NT * 4) {
            const float4 pv = *(const float4*)(prev + rowOff + m);
            float pr0 = 1.f, pr1 = 1.f, pr2 = 1.f, pr3 = 1.f;
            #pragma unroll
            for (int w = 0; w < Wl; ++w) {
                const float4 a = *(const float4*)(ww + ((size_t)b * Wl + w) * M + m);
                pr0 *= (1.0f - a.x); pr1 *= (1.0f - a.y);
                pr2 *= (1.0f - a.z); pr3 *= (1.0f - a.w);
            }
            float u0 = pv.x + (1.0f - pv.x) * (1.0f - pr0);
            float u1 = pv.y + (1.0f - pv.y) * (1.0f - pr1);
            float u2 = pv.z + (1.0f - pv.z) * (1.0f - pr2);
            float u3 = pv.w + (1.0f - pv.w) * (1.0f - pr3);
            float f0 = 1.f, f1 = 1.f, f2 = 1.f, f3 = 1.f;
            #pragma unroll
            for (int r = 0; r < Rl; ++r) {
                const float fr = frs[r];
                const float4 a = *(const float4*)(rw + ((size_t)b * Rl + r) * M + m);
                f0 *= (1.0f - fr * a.x); f1 *= (1.0f - fr * a.y);
                f2 *= (1.0f - fr * a.z); f3 *= (1.0f - fr * a.w);
            }
            float4 uo;
            uo.x = u0 * f0; uo.y = u1 * f1; uo.z = u2 * f2; uo.w = u3 * f3;
            *(float4*)(out_usage + rowOff + m) = uo;    // regular store: keep L2-hot
            if (TW == 0) {
                const float4 z = make_float4(0.f, 0.f, 0.f, 0.f);
                for (int w = 0; w < Wl; ++w)
                    nt_store4(out_alloc + ((size_t)b * Wl + w) * M + m, z);
            }
            const float ua[4] = {uo.x, uo.y, uo.z, uo.w};
            #pragma unroll
            for (int j = 0; j < 4; ++j) {
                const float nn = 1.0f - (CE + C1 * ua[j]);
                atomicAdd(&hC[bucket_of(__float_as_uint(nn))], 1u);
            }
        }
    }
    __syncthreads();   // usage visible in L2; hist complete

    // ---------------- Pool cut: min x with suffix-count <= POOLCAP ----------------
    {
        const bool act = (t < NBINS);
        u32 sc = 0; int x = 0;
        if (act) {
            x = NBINS - 1 - t;
            sc = hC[x];
            #pragma unroll
            for (int off = 1; off < 64; off <<= 1) {
                const u32 oc = __shfl_up(sc, off);
                if (lane >= off) sc += oc;
            }
            if (lane == 63) tc[wid] = sc;
        }
        __syncthreads();
        if (act) {
            u32 ac = 0;
            for (int q = 0; q < wid; ++q) ac += tc[q];
            sc += ac;
            if (sc <= (u32)POOLCAP) atomicMin(&misc[3], x);
        }
    }
    __syncthreads();
    const int pc = misc[3];

    // ---------------- Pool build: one L2-hot re-read of this row's usage ----------------
    for (int m = t * 4; m < M; m += NT * 4) {
        const float4 uu = *(const float4*)(out_usage + rowOff + m);
        const float ua[4] = {uu.x, uu.y, uu.z, uu.w};
        #pragma unroll
        for (int j = 0; j < 4; ++j) {
            const float ue = CE + C1 * ua[j];
            const float nn = 1.0f - ue;
            const u32 nnbits = __float_as_uint(nn);
            const int bkt = bucket_of(nnbits);
            const bool pred = (bkt >= pc) && (pc < NBINS);
            const u64 mask = __ballot(pred);
            const int cnt = __popcll(mask);
            if (cnt) {
                int base = 0;
                if (lane == 0) base = atomicAdd(&misc[0], cnt);
                base = __shfl(base, 0);
                if (pred) {
                    const int pos = base + __popcll(mask & ((1ull << lane) - 1));
                    if (pos < POOLCAP) {
                        poolKey[pos] = (((u64)(~nnbits)) << 16) | (u64)(u32)(m + j);
                        poolLg[pos] = __log2f(ue);
                    }
                }
            }
        }
    }
    __syncthreads();
    int P = misc[0]; if (P > POOLCAP) P = POOLCAP;

    // ---------------- Phase H: per write head (pool-only) ----------------
    for (int i = 0; i < Wl; ++i) {
        const float wgi = wgt[(size_t)b * Wl + i];
        float* orow = out_alloc + ((size_t)b * Wl + i) * M;

        if (t == 0) { misc[4] = 0; misc[1] = -1; misc[2] = NBINS; }
        __syncthreads();   // orders prior-head pool/hist updates

        // suffix scan over persistent hist: count + bounded mass; gated to x >= pc
        {
            const bool act = (t < NBINS);
            u32 sc = 0; float sw = 0.f; int x = 0;
            if (act) {
                x = NBINS - 1 - t;
                const u32 c = hC[x];
                sc = c;
                sw = mB[x] * (float)c;
                #pragma unroll
                for (int off = 1; off < 64; off <<= 1) {
                    const u32  oc = __shfl_up(sc, off);
                    const float ow = __shfl_up(sw, off);
                    if (lane >= off) { sc += oc; sw += ow; }
                }
                if (lane == 63) { tc[wid] = sc; twv[wid] = sw; }
            }
            __syncthreads();
            if (act) {
                u32 ac = 0; float aw = 0.f;
                for (int q = 0; q < wid; ++q) { ac += tc[q]; aw += twv[q]; }
                sc += ac; sw += aw;
                if (x >= pc) {
                    if (sw <= LOG_CUT) atomicMax(&misc[1], x);   // enough log-mass
                    if (sc <= (u32)CAP) atomicMin(&misc[2], x);  // within count cap
                }
            }
        }
        __syncthreads();
        const int xs = misc[1];
        const int xc = misc[2];
        const int cut = (xs > xc) ? xs : xc;

        // compact candidates from the POOL (1 iter: P <= 1024 = NT)
        if (t < P) {
            const u64 key = poolKey[t];
            const u32 nnbits = ~((u32)(key >> 16));
            const int bkt = bucket_of(nnbits);
            const bool pred = (bkt >= cut) && (cut < NBINS);
            const u64 mask = __ballot(pred);
            const int cnt = __popcll(mask);
            if (cnt) {
                int base = 0;
                if (lane == 0) base = atomicAdd(&misc[4], cnt);
                base = __shfl(base, 0);
                if (pred) {
                    const int pos = base + __popcll(mask & ((1ull << lane) - 1));
                    if (pos < CAP) {
                        candKey[pos] = key;
                        candLg[pos] = poolLg[t];
                        candPos[pos] = (u16)t;
                    }
                }
            }
        }
        __syncthreads();
        int K = misc[4]; if (K > CAP) K = CAP;

        // 4-way parallel pairwise rank: thread (c, g=t>>8) sums group g's quarter
        const int c = t & (CAP - 1);
        const int g = t >> 8;
        float Sp = 0.0f;
        if (c < K) {
            const u64 mykey = candKey[c];
            const int k0 = (K * g) >> 2;
            const int k1 = (K * (g + 1)) >> 2;
            for (int k = k0; k < k1; ++k) {
                if (candKey[k] < mykey) Sp += candLg[k];
            }
        }
        if (g > 0) sPart[g - 1][c] = Sp;
        __syncthreads();

        float myAl = 0.0f; int myIdx = -1;
        if (t < K) {   // g == 0, c == t
            const float S = Sp + sPart[0][t] + sPart[1][t] + sPart[2][t];
            const u64 mykey = candKey[t];
            const u32 nnbits = ~((u32)(mykey >> 16));
            const float nn = __uint_as_float(nnbits);
            const int idx = (int)(mykey & 0xFFFFull);
            const float al = nn * __builtin_exp2f(S);
            if (al != 0.0f) {
                if (TW > 0) {
                    myAl = al; myIdx = idx;
                    atomicOr(&bmS[i][idx >> 6], 1ull << (idx & 63));
                } else {
                    orow[idx] = al;          // generic: direct scatter (rows pre-zeroed)
                }
                if (i + 1 < Wl) {
                    // current usage u: ue = CE + C1*u = 1-nn  =>  u = (1-nn-CE)/C1
                    const float ucur = (1.0f - nn - CE) / C1;
                    const float unew = ucur + ((1.0f - ucur) * wgi) * al;
                    const float nn2 = 1.0f - (CE + C1 * unew);
                    const u32 nn2bits = __float_as_uint(nn2);
                    const int p = (int)candPos[t];
                    poolKey[p] = (((u64)(~nn2bits)) << 16) | (u64)(u32)idx;
                    poolLg[p] = __log2f(1.0f - nn2);
                    const int bold = bucket_of(nnbits);
                    const int bnew = bucket_of(nn2bits);
                    if (bnew != bold) {
                        atomicSub(&hC[bold], 1u);
                        atomicAdd(&hC[bnew], 1u);
                    }
                }
            }
        }
        if (TW > 0) {
            __syncthreads();   // bitmap complete
            // exclusive popcount prefix over this head's bitmap words (MWW=256)
            u32 myinc = 0, mycnt = 0;
            if (t < MWW) {
                mycnt = (u32)__popcll(bmS[i][t]);
                myinc = mycnt;
                #pragma unroll
                for (int off = 1; off < 64; off <<= 1) {
                    const u32 o = __shfl_up(myinc, off);
                    if (lane >= off) myinc += o;
                }
                if (lane == 63) tc[wid] = myinc;
            }
            __syncthreads();
            if (t < MWW) {
                u32 add = 0;
                for (int q = 0; q < wid; ++q) add += tc[q];
                boS[i][t] = myinc + add - mycnt;
            }
            __syncthreads();
            // deposit value at row-rank slot
            if (myIdx >= 0) {
                const u64 wb = bmS[i][myIdx >> 6];
                const int xr = (int)boS[i][myIdx >> 6]
                             + (int)__popcll(wb & ((1ull << (myIdx & 63)) - 1));
                valS[i][xr] = myAl;
            }
        }
        __syncthreads();
    }

    // ---------------- Final sweep: dense pure-write of all alloc rows ----------------
    if (TW > 0) {
        for (int m4 = t * 4; m4 < M; m4 += NT * 4) {
            const int word = m4 >> 6;
            const int bit0 = m4 & 63;
            #pragma unroll
            for (int w = 0; w < TW; ++w) {
                const u64 wb = bmS[w][word];
                float4 o = make_float4(0.f, 0.f, 0.f, 0.f);
                if ((wb >> bit0) & 15ull) {
                    int base = (int)boS[w][word]
                             + (int)__popcll(wb & ((1ull << bit0) - 1));
                    float* op = &o.x;
                    #pragma unroll
                    for (int j = 0; j < 4; ++j) {
                        if ((wb >> (bit0 + j)) & 1ull) op[j] = valS[w][base++];
                    }
                }
                nt_store4(out_alloc + ((size_t)b * TW + w) * M + m4, o);
            }
        }
    }
}

extern "C" void kernel_launch(void* const* d_in, const int* in_sizes, int n_in,
                              void* d_out, int out_size, void* d_ws, size_t ws_size,
                              hipStream_t stream) {
    const float* ww   = (const float*)d_in[0];
    const float* fg   = (const float*)d_in[1];
    const float* rw   = (const float*)d_in[2];
    const float* prev = (const float*)d_in[3];
    const float* wgt  = (const float*)d_in[4];
    const int BWM = in_sizes[0];
    const int BR  = in_sizes[1];
    const int BM  = in_sizes[3];
    const int BW  = in_sizes[4];
    const int M = BWM / BW;
    const int B = BM / M;
    const int W = BW / B;
    const int R = BR / B;

    float* out_usage = (float*)d_out;
    float* out_alloc = out_usage + (size_t)BM;

    if (W == 4 && R == 8 && M == 16384) {
        hipLaunchKernelGGL((fused_kernel<4, 8>), dim3(B), dim3(NT), 0, stream,
                           ww, fg, rw, prev, wgt, out_usage, out_alloc, B, W, R, M);
    } else {
        hipLaunchKernelGGL((fused_kernel<0, 0>), dim3(B), dim3(NT), 0, stream,
                           ww, fg, rw, prev, wgt, out_usage, out_alloc, B, W, R, M);
    }
}